// Round 3
// baseline (596.539 us; speedup 1.0000x reference)
//
#include <hip/hip_runtime.h>

// out_fp = (a*scale_a)*(b*scale_b); out_q = clip(rint(out_fp/scale_out), -128, 127)
// a,b int8-in-reference delivered as int32 (const int*), N = 16*4096*1024 = 67108864.
// scales float32 (D=1024). d_out = float[N] quantized values ++ float[D] scale_out.
//
// R1 lesson: VGPR_Count=8 => compiler serialized the two loads, MLP~1, 3 TB/s.
// R2/R3: unroll x4 per thread (block-strided so each load instr stays coalesced),
// batch all 8 int4 loads into registers before first use, nontemporal stores
// (via clang ext_vector_type — HIP float4 struct is rejected by the builtin).

typedef float vf4 __attribute__((ext_vector_type(4)));

__global__ void prep_scales_kernel(const float* __restrict__ sa,
                                   const float* __restrict__ sb,
                                   const float* __restrict__ so,
                                   float* __restrict__ c,
                                   float* __restrict__ out_tail,
                                   int D) {
    int d = blockIdx.x * blockDim.x + threadIdx.x;
    if (d < D) {
        float s = so[d];
        c[d] = sa[d] * sb[d] / s;   // exact IEEE divide, once per column
        out_tail[d] = s;            // second tuple output: scale_out passthrough
    }
}

#define TPB 256u
#define UNROLL 4u

__global__ __launch_bounds__(TPB) void mulq_kernel(const int4* __restrict__ a,
                                                   const int4* __restrict__ b,
                                                   const float* __restrict__ c,
                                                   vf4* __restrict__ out,
                                                   unsigned dmask, unsigned use_mask,
                                                   unsigned D, unsigned nvec) {
    // vec index of this thread's k-th chunk: base + k*TPB (lane-consecutive per k)
    const unsigned base = blockIdx.x * (TPB * UNROLL) + threadIdx.x;

    if (base + (UNROLL - 1u) * TPB < nvec) {
        // fast path: all UNROLL vecs in range -> straight-line batched loads
        int4 av[UNROLL], bv[UNROLL];
#pragma unroll
        for (unsigned k = 0; k < UNROLL; ++k) av[k] = a[base + k * TPB];
#pragma unroll
        for (unsigned k = 0; k < UNROLL; ++k) bv[k] = b[base + k * TPB];

#pragma unroll
        for (unsigned k = 0; k < UNROLL; ++k) {
            const unsigned idx = base + k * TPB;
            const unsigned e0 = idx * 4u;
            const unsigned d = use_mask ? (e0 & dmask) : (e0 % D);
            const float4 cv = *(const float4*)(c + d);   // L1-resident (4 KiB table)
            vf4 o;
            o.x = fminf(fmaxf(rintf((float)(av[k].x * bv[k].x) * cv.x), -128.0f), 127.0f);
            o.y = fminf(fmaxf(rintf((float)(av[k].y * bv[k].y) * cv.y), -128.0f), 127.0f);
            o.z = fminf(fmaxf(rintf((float)(av[k].z * bv[k].z) * cv.z), -128.0f), 127.0f);
            o.w = fminf(fmaxf(rintf((float)(av[k].w * bv[k].w) * cv.w), -128.0f), 127.0f);
            __builtin_nontemporal_store(o, &out[idx]);   // keep write stream out of L3
        }
    } else {
        // tail path (unused at N=67108864, kept for generality)
#pragma unroll
        for (unsigned k = 0; k < UNROLL; ++k) {
            const unsigned idx = base + k * TPB;
            if (idx >= nvec) continue;
            const unsigned e0 = idx * 4u;
            const unsigned d = use_mask ? (e0 & dmask) : (e0 % D);
            const int4 av = a[idx];
            const int4 bv = b[idx];
            const float4 cv = *(const float4*)(c + d);
            vf4 o;
            o.x = fminf(fmaxf(rintf((float)(av.x * bv.x) * cv.x), -128.0f), 127.0f);
            o.y = fminf(fmaxf(rintf((float)(av.y * bv.y) * cv.y), -128.0f), 127.0f);
            o.z = fminf(fmaxf(rintf((float)(av.z * bv.z) * cv.z), -128.0f), 127.0f);
            o.w = fminf(fmaxf(rintf((float)(av.w * bv.w) * cv.w), -128.0f), 127.0f);
            __builtin_nontemporal_store(o, &out[idx]);
        }
    }
}

extern "C" void kernel_launch(void* const* d_in, const int* in_sizes, int n_in,
                              void* d_out, int out_size, void* d_ws, size_t ws_size,
                              hipStream_t stream) {
    const int*   a  = (const int*)  d_in[0];
    const float* sa = (const float*)d_in[1];
    const int*   b  = (const int*)  d_in[2];
    const float* sb = (const float*)d_in[3];
    const float* so = (const float*)d_in[4];

    const int N = in_sizes[0];   // 67108864
    const int D = in_sizes[1];   // 1024

    float* out = (float*)d_out;
    float* c   = (float*)d_ws;   // D floats of scratch (4 KiB)

    prep_scales_kernel<<<(D + 255) / 256, 256, 0, stream>>>(sa, sb, so, c, out + (size_t)N, D);

    const unsigned nvec = (unsigned)(N / 4);
    const unsigned use_mask = ((D & (D - 1)) == 0) ? 1u : 0u;
    const unsigned per_block = TPB * UNROLL;
    const unsigned nblocks = (nvec + per_block - 1u) / per_block;
    mulq_kernel<<<nblocks, TPB, 0, stream>>>(
        (const int4*)a, (const int4*)b, c, (vf4*)out,
        (unsigned)(D - 1), use_mask, (unsigned)D, nvec);
}

// Round 4
// 567.202 us; speedup vs baseline: 1.0517x; 1.0517x over previous
//
#include <hip/hip_runtime.h>

// out_fp = (a*scale_a)*(b*scale_b); out_q = clip(rint(out_fp/scale_out), -128, 127)
// a,b int8-in-reference delivered as int32 (const int*), N = 16*4096*1024 = 67108864.
// scales float32 (D=1024). d_out = float[N] quantized values ++ float[D] scale_out.
//
// R1: simple 1x int4-pair/thread, plain ld/st -> 176 us, 4.6 TB/s demand.
// R3: UNROLL4 + nt STORES -> 208 us regression (nt stores fight the L3-resident
//     poisoned output lines; MLP was never the limiter at 80% occupancy).
// R4: exact R1 structure + nt LOADS only (read-once inputs: don't allocate in
//     L2/L3 on miss, keep cache capacity for the write stream). Plain stores.

typedef int   vi4 __attribute__((ext_vector_type(4)));
typedef float vf4 __attribute__((ext_vector_type(4)));

__global__ void prep_scales_kernel(const float* __restrict__ sa,
                                   const float* __restrict__ sb,
                                   const float* __restrict__ so,
                                   float* __restrict__ c,
                                   float* __restrict__ out_tail,
                                   int D) {
    int d = blockIdx.x * blockDim.x + threadIdx.x;
    if (d < D) {
        float s = so[d];
        c[d] = sa[d] * sb[d] / s;   // exact IEEE divide, once per column
        out_tail[d] = s;            // second tuple output: scale_out passthrough
    }
}

__global__ __launch_bounds__(256) void mulq_kernel(const vi4* __restrict__ a,
                                                   const vi4* __restrict__ b,
                                                   const float* __restrict__ c,
                                                   vf4* __restrict__ out,
                                                   unsigned dmask, unsigned use_mask,
                                                   unsigned D, unsigned nvec) {
    unsigned tid = blockIdx.x * blockDim.x + threadIdx.x;
    if (tid >= nvec) return;
    unsigned e0 = tid * 4u;                          // first element index
    unsigned d = use_mask ? (e0 & dmask) : (e0 % D); // column index (mult of 4)

    vi4 av = __builtin_nontemporal_load(&a[tid]);    // read-once: no L2/L3 alloc
    vi4 bv = __builtin_nontemporal_load(&b[tid]);
    float4 cv = *(const float4*)(c + d);             // 4 KiB table, cache-resident

    vf4 o;
    o.x = fminf(fmaxf(rintf((float)(av.x * bv.x) * cv.x), -128.0f), 127.0f);
    o.y = fminf(fmaxf(rintf((float)(av.y * bv.y) * cv.y), -128.0f), 127.0f);
    o.z = fminf(fmaxf(rintf((float)(av.z * bv.z) * cv.z), -128.0f), 127.0f);
    o.w = fminf(fmaxf(rintf((float)(av.w * bv.w) * cv.w), -128.0f), 127.0f);

    out[tid] = o;                                    // plain store (L3-friendly)
}

extern "C" void kernel_launch(void* const* d_in, const int* in_sizes, int n_in,
                              void* d_out, int out_size, void* d_ws, size_t ws_size,
                              hipStream_t stream) {
    const int*   a  = (const int*)  d_in[0];
    const float* sa = (const float*)d_in[1];
    const int*   b  = (const int*)  d_in[2];
    const float* sb = (const float*)d_in[3];
    const float* so = (const float*)d_in[4];

    const int N = in_sizes[0];   // 67108864
    const int D = in_sizes[1];   // 1024

    float* out = (float*)d_out;
    float* c   = (float*)d_ws;   // D floats of scratch (4 KiB)

    prep_scales_kernel<<<(D + 255) / 256, 256, 0, stream>>>(sa, sb, so, c, out + (size_t)N, D);

    const unsigned nvec = (unsigned)(N / 4);
    const unsigned use_mask = ((D & (D - 1)) == 0) ? 1u : 0u;
    mulq_kernel<<<(nvec + 255u) / 256u, 256, 0, stream>>>(
        (const vi4*)a, (const vi4*)b, c, (vf4*)out,
        (unsigned)(D - 1), use_mask, (unsigned)D, nvec);
}